// Round 9
// baseline (428.854 us; speedup 1.0000x reference)
//
#include <hip/hip_runtime.h>
#include <hip/hip_bf16.h>

typedef __bf16 bf16_t;
typedef __bf16 bf16x4 __attribute__((ext_vector_type(4)));
typedef __bf16 bf16x8 __attribute__((ext_vector_type(8)));
typedef float  f32x4  __attribute__((ext_vector_type(4)));
typedef float  f32x8  __attribute__((ext_vector_type(8)));
typedef unsigned int u32;
typedef u32 u32x4 __attribute__((ext_vector_type(4)));

#define EMBED 512
#define NH    8
#define HD    64
#define SEQ   2048
#define MTOT  8192
#define SCQ   0.18033688011112042f   // log2(e) / sqrt(64), folded into Q
#define NBLK  512                    // persistent grid: 2 x 256 CUs exactly

__device__ __forceinline__ float gelu_f(float x) {
    return 0.5f * x * (1.0f + erff(x * 0.7071067811865475f));
}

__device__ __forceinline__ f32x4 mfma16(bf16x8 a, bf16x8 b, f32x4 c) {
    return __builtin_amdgcn_mfma_f32_16x16x32_bf16(a, b, c, 0, 0, 0);
}

// Raw barrier: LDS-write visibility only (lgkmcnt(0)), NO vmcnt drain.
__device__ __forceinline__ void barrier_nodrain() {
    asm volatile("s_waitcnt lgkmcnt(0)" ::: "memory");
    __builtin_amdgcn_s_barrier();
    asm volatile("" ::: "memory");
}

// T12 primitives (flash): pack 2 f32 -> 2 bf16, cross-lane register swaps.
__device__ __forceinline__ u32 cvtpk_bf16(float lo, float hi) {
    u32 r;
    asm("v_cvt_pk_bf16_f32 %0, %1, %2" : "=v"(r) : "v"(lo), "v"(hi));
    return r;
}
__device__ __forceinline__ void swap32(u32& a, u32& b) {
    asm volatile("v_permlane32_swap_b32 %0, %1" : "+v"(a), "+v"(b));
}
__device__ __forceinline__ void swap16(u32& a, u32& b) {
    asm volatile("v_permlane16_swap_b32 %0, %1" : "+v"(a), "+v"(b));
}

// ---------------------------------------------------------------------------
// Grid barrier (sense-reversal). All NBLK blocks are co-resident by
// construction (grid = 2 x 256 CUs, __launch_bounds__(256,2), LDS 36.8KB).
// bar[0]=arrive count, bar[1]=generation; zeroed per replay via memset node.
// __threadfence (device scope) provides cross-XCD L2 writeback/invalidate
// around the atomics (m20: global atomics are device-scope).
// ---------------------------------------------------------------------------
__device__ __forceinline__ void gbar(u32* bar) {
    __threadfence();
    __syncthreads();
    if (threadIdx.x == 0) {
        const u32 g = atomicAdd(&bar[1], 0u);        // read gen BEFORE arriving
        const u32 v = atomicAdd(&bar[0], 1u);
        if (v == NBLK - 1u) {
            atomicExch(&bar[0], 0u);                 // reset for next use
            __threadfence();
            atomicAdd(&bar[1], 1u);                  // release
        } else {
            while (atomicAdd(&bar[1], 0u) == g) __builtin_amdgcn_s_sleep(2);
        }
    }
    __syncthreads();
    __threadfence();
}

// ---------------------------------------------------------------------------
// GEMM + bias + GELU phase body (R8 code, verbatim; blockIdx -> bx/by).
// MODE 0 (QKV): x fp32 A-prefetch + inline fp32 W convert (fused convert).
// MODE 1 (out): bf16 A-prefetch + inline fp32 Wo convert.
// ---------------------------------------------------------------------------
template<int MODE, int NTILE>
__device__ __forceinline__
void gemm_body(int bx, int by, const void* __restrict__ Xp,
               const float* __restrict__ W0, const float* __restrict__ W1,
               const float* __restrict__ W2,
               const float* __restrict__ Bq, const float* __restrict__ Bk,
               const float* __restrict__ Bv,
               bf16_t* __restrict__ O0, bf16_t* __restrict__ O1,
               bf16_t* __restrict__ O2, float* __restrict__ Of,
               bf16_t* As, bf16_t* Bs)
{
    constexpr int NTN = NTILE / 32;
    const int tid  = threadIdx.x;
    const int lane = tid & 63, w = tid >> 6, quad = lane >> 4, l15 = lane & 15;
    const int m0 = bx * 128;
    int mat, n0;
    if (MODE == 0) { mat = by >> 2; n0 = (by & 3) * NTILE; }
    else           { mat = 0;       n0 = by * NTILE; }
    const float* W  = (MODE == 0) ? (mat == 0 ? W0 : (mat == 1 ? W1 : W2)) : W0;
    const float* Bi = (MODE == 1) ? Bq : (mat == 0 ? Bq : (mat == 1 ? Bk : Bv));
    const float*  Xf = (const float*)Xp;    // MODE 0
    const bf16_t* Xb = (const bf16_t*)Xp;   // MODE 1

    const int wr = (w >> 1) * 64;
    const int wc = (w & 1) * (NTILE / 2);
    const int srow = tid >> 3, scol = (tid & 7) * 8;

    f32x4 acc[4][NTN];
#pragma unroll
    for (int a = 0; a < 4; ++a)
#pragma unroll
        for (int b = 0; b < NTN; ++b) acc[a][b] = f32x4{0.f, 0.f, 0.f, 0.f};

    f32x8  xpf[4];
    bf16x8 xpb[4];
#pragma unroll
    for (int it = 0; it < 4; ++it) {
        const size_t r = (size_t)(m0 + it * 32 + srow);
        if (MODE == 0) xpf[it] = *(const f32x8*)(Xf + r * EMBED + scol);
        else           xpb[it] = *(const bf16x8*)(Xb + r * EMBED + scol);
    }

#pragma unroll 1
    for (int kt = 0; kt < 8; ++kt) {
        const int k0 = kt * 64;
        barrier_nodrain();
#pragma unroll
        for (int it = 0; it < 4; ++it) {
            if (MODE == 0)
                *(bf16x8*)(As + (it * 32 + srow) * 72 + scol) =
                    __builtin_convertvector(xpf[it], bf16x8);
            else
                *(bf16x8*)(As + (it * 32 + srow) * 72 + scol) = xpb[it];
        }
#pragma unroll
        for (int it = 0; it < NTN; ++it) {
            const int r = it * 32 + srow;
            const f32x8 wv = *(const f32x8*)(W + (size_t)(n0 + r) * EMBED + k0 + scol);
            *(bf16x8*)(Bs + r * 72 + scol) = __builtin_convertvector(wv, bf16x8);
        }
        if (kt < 7) {
            const int k1 = k0 + 64;
#pragma unroll
            for (int it = 0; it < 4; ++it) {
                const size_t r = (size_t)(m0 + it * 32 + srow);
                if (MODE == 0) xpf[it] = *(const f32x8*)(Xf + r * EMBED + k1 + scol);
                else           xpb[it] = *(const bf16x8*)(Xb + r * EMBED + k1 + scol);
            }
        }
        barrier_nodrain();
#pragma unroll
        for (int ks = 0; ks < 2; ++ks) {
            const int ko = (ks * 4 + quad) * 8;
            bf16x8 av[4], bv[NTN];
#pragma unroll
            for (int mt = 0; mt < 4; ++mt)
                av[mt] = *(const bf16x8*)(As + (wr + mt * 16 + l15) * 72 + ko);
#pragma unroll
            for (int nt = 0; nt < NTN; ++nt)
                bv[nt] = *(const bf16x8*)(Bs + (wc + nt * 16 + l15) * 72 + ko);
#pragma unroll
            for (int mt = 0; mt < 4; ++mt)
#pragma unroll
                for (int nt = 0; nt < NTN; ++nt)
                    acc[mt][nt] = mfma16(av[mt], bv[nt], acc[mt][nt]);
        }
    }

    float biasv[NTN];
#pragma unroll
    for (int nt = 0; nt < NTN; ++nt)
        biasv[nt] = Bi[n0 + wc + nt * 16 + l15];
#pragma unroll
    for (int mt = 0; mt < 4; ++mt) {
        const int mb = m0 + wr + mt * 16 + quad * 4;
        const int bb = mb >> 11, s0 = mb & (SEQ - 1);
#pragma unroll
        for (int nt = 0; nt < NTN; ++nt) {
            const int fc = n0 + wc + nt * 16 + l15;
            const int h = fc >> 6, d = fc & 63;
            float vv[4];
#pragma unroll
            for (int i = 0; i < 4; ++i) vv[i] = gelu_f(acc[mt][nt][i] + biasv[nt]);
            if (MODE == 1) {
#pragma unroll
                for (int i = 0; i < 4; ++i) Of[(size_t)(mb + i) * EMBED + fc] = vv[i];
            } else if (mat == 0) {
#pragma unroll
                for (int i = 0; i < 4; ++i)
                    O0[(((size_t)(bb * NH + h)) * SEQ + s0 + i) * HD + d] = (bf16_t)(vv[i] * SCQ);
            } else if (mat == 1) {
#pragma unroll
                for (int i = 0; i < 4; ++i)
                    O1[(((size_t)(bb * NH + h)) * SEQ + s0 + i) * HD + d] = (bf16_t)vv[i];
            } else {
                bf16x4 pk;
#pragma unroll
                for (int i = 0; i < 4; ++i) pk[i] = (bf16_t)vv[i];
                *(bf16x4*)(O2 + ((size_t)(bb * NH + h) * HD + d) * SEQ + s0) = pk;
            }
        }
    }
}

// ---------------------------------------------------------------------------
// Flash attention phase body — R5-R8 code verbatim (67.4-68.4 µs stable,
// conflicts 0, T12 in-reg P); Ks/Vs become pointers into the shared arena.
// ---------------------------------------------------------------------------
#define FA_ITER(T, BUF, KR0, KR1, VR0, VR1)                                   \
    do {                                                                      \
        if ((T) + 1 < 32) {                                                   \
            bf16_t* Kn = KS + (((BUF) ^ 1) << 12);                            \
            bf16_t* Vn = VS + (((BUF) ^ 1) << 12);                            \
            *(bf16x8*)(Kn + sA)        = KR0;                                 \
            *(bf16x8*)(Kn + sA + 2048) = KR1;                                 \
            *(bf16x8*)(Vn + sA)        = VR0;                                 \
            *(bf16x8*)(Vn + sA + 2048) = VR1;                                 \
        }                                                                     \
        if ((T) + 3 < 32) {                                                   \
            const int kv = ((T) + 3) * 64;                                    \
            KR0 = *(const bf16x8*)(K + baseQK + (size_t)(kv + r0) * HD + c0); \
            KR1 = *(const bf16x8*)(K + baseQK + (size_t)(kv + r0 + 32) * HD + c0); \
            VR0 = *(const bf16x8*)(Vt + baseV + (size_t)r0 * SEQ + kv + c0);  \
            VR1 = *(const bf16x8*)(Vt + baseV + (size_t)(r0 + 32) * SEQ + kv + c0); \
        }                                                                     \
        const bf16_t* Kb = KS + ((BUF) << 12);                                \
        const bf16_t* Vb = VS + ((BUF) << 12);                                \
        f32x4 sf[4];                                                          \
        _Pragma("unroll")                                                     \
        for (int jt = 0; jt < 4; ++jt) sf[jt] = f32x4{0.f, 0.f, 0.f, 0.f};    \
        __builtin_amdgcn_s_setprio(1);                                        \
        _Pragma("unroll")                                                     \
        for (int ks = 0; ks < 2; ++ks) {                                      \
            const int ko = (ks * 32 + quad * 8) ^ cx;                         \
            _Pragma("unroll")                                                 \
            for (int jt = 0; jt < 4; ++jt) {                                  \
                const bf16x8 a = *(const bf16x8*)(Kb + ((jt * 16 + l15) << 6) + ko); \
                sf[jt] = mfma16(a, qf[ks], sf[jt]);                           \
            }                                                                 \
        }                                                                     \
        __builtin_amdgcn_s_setprio(0);                                        \
        u32 w0[4], w1[4];                                                     \
        _Pragma("unroll")                                                     \
        for (int jt = 0; jt < 4; ++jt) {                                      \
            _Pragma("unroll")                                                 \
            for (int i = 0; i < 4; ++i) sf[jt][i] = exp2f(sf[jt][i]);         \
            lacc += sf[jt];                                                   \
            w0[jt] = cvtpk_bf16(sf[jt][0], sf[jt][1]);                        \
            w1[jt] = cvtpk_bf16(sf[jt][2], sf[jt][3]);                        \
        }                                                                     \
        swap32(w0[0], w0[1]); swap16(w0[0], w0[1]);                           \
        swap32(w1[0], w1[1]); swap16(w1[0], w1[1]);                           \
        swap32(w0[2], w0[3]); swap16(w0[2], w0[3]);                           \
        swap32(w1[2], w1[3]); swap16(w1[2], w1[3]);                           \
        const u32x4 pq0 = u32x4{w0[0], w1[0], w0[1], w1[1]};                  \
        const u32x4 pq1 = u32x4{w0[2], w1[2], w0[3], w1[3]};                  \
        const bf16x8 pa0 = __builtin_bit_cast(bf16x8, pq0);                   \
        const bf16x8 pa1 = __builtin_bit_cast(bf16x8, pq1);                   \
        __builtin_amdgcn_s_setprio(1);                                        \
        _Pragma("unroll")                                                     \
        for (int c = 0; c < 2; ++c) {                                         \
            const int ko = (c * 32 + quad * 8) ^ cx;                          \
            const bf16x8 pa = c ? pa1 : pa0;                                  \
            _Pragma("unroll")                                                 \
            for (int nt = 0; nt < 4; ++nt) {                                  \
                const bf16x8 b = *(const bf16x8*)(Vb + ((nt * 16 + l15) << 6) + ko); \
                oacc[nt] = mfma16(pa, b, oacc[nt]);                           \
            }                                                                 \
        }                                                                     \
        __builtin_amdgcn_s_setprio(0);                                        \
        if ((T) < 31) barrier_nodrain();                                      \
    } while (0)

__device__ __forceinline__
void flash_body(int t, const bf16_t* __restrict__ Q, const bf16_t* __restrict__ K,
                const bf16_t* __restrict__ Vt, bf16_t* __restrict__ Og,
                bf16_t* KS, bf16_t* VS)
{
    const int tid  = threadIdx.x;
    const int lane = tid & 63, w = tid >> 6, quad = lane >> 4, l15 = lane & 15;
    const int bh = t >> 5;
    const int q0 = (t & 31) * 64;
    const size_t baseQK = (size_t)bh * SEQ * HD;
    const size_t baseV  = (size_t)bh * HD * SEQ;
    const int wm = w * 16;
    const int cx = (l15 & 7) << 3;

    bf16x8 qf[2];
#pragma unroll
    for (int ks = 0; ks < 2; ++ks)
        qf[ks] = *(const bf16x8*)(Q + baseQK + (size_t)(q0 + wm + l15) * HD + ks * 32 + quad * 8);

    f32x4 lacc = f32x4{0.f, 0.f, 0.f, 0.f};
    f32x4 oacc[4];
#pragma unroll
    for (int nt = 0; nt < 4; ++nt) oacc[nt] = f32x4{0.f, 0.f, 0.f, 0.f};

    const int r0 = tid >> 3, c0 = (tid & 7) * 8;
    const int sA = (r0 << 6) + (c0 ^ ((r0 & 7) << 3));

    bf16x8 kA0, kA1, vA0, vA1;
    bf16x8 kB0, kB1, vB0, vB1;

    kA0 = *(const bf16x8*)(K + baseQK + (size_t)r0 * HD + c0);
    kA1 = *(const bf16x8*)(K + baseQK + (size_t)(r0 + 32) * HD + c0);
    vA0 = *(const bf16x8*)(Vt + baseV + (size_t)r0 * SEQ + c0);
    vA1 = *(const bf16x8*)(Vt + baseV + (size_t)(r0 + 32) * SEQ + c0);
    *(bf16x8*)(KS + sA)        = kA0;
    *(bf16x8*)(KS + sA + 2048) = kA1;
    *(bf16x8*)(VS + sA)        = vA0;
    *(bf16x8*)(VS + sA + 2048) = vA1;
    kB0 = *(const bf16x8*)(K + baseQK + (size_t)(64 + r0) * HD + c0);
    kB1 = *(const bf16x8*)(K + baseQK + (size_t)(64 + r0 + 32) * HD + c0);
    vB0 = *(const bf16x8*)(Vt + baseV + (size_t)r0 * SEQ + 64 + c0);
    vB1 = *(const bf16x8*)(Vt + baseV + (size_t)(r0 + 32) * SEQ + 64 + c0);
    kA0 = *(const bf16x8*)(K + baseQK + (size_t)(128 + r0) * HD + c0);
    kA1 = *(const bf16x8*)(K + baseQK + (size_t)(128 + r0 + 32) * HD + c0);
    vA0 = *(const bf16x8*)(Vt + baseV + (size_t)r0 * SEQ + 128 + c0);
    vA1 = *(const bf16x8*)(Vt + baseV + (size_t)(r0 + 32) * SEQ + 128 + c0);
    barrier_nodrain();

#pragma unroll 1
    for (int tt = 0; tt < 32; tt += 2) {
        FA_ITER(tt,     0, kB0, kB1, vB0, vB1);
        FA_ITER(tt + 1, 1, kA0, kA1, vA0, vA1);
    }

    const int bidx = bh >> 3, h = bh & 7;
    float rs = (lacc[0] + lacc[1]) + (lacc[2] + lacc[3]);
    rs += __shfl_xor(rs, 16);
    rs += __shfl_xor(rs, 32);
    float lf[4];
#pragma unroll
    for (int i = 0; i < 4; ++i)
        lf[i] = __shfl(rs, (lane & 48) | (quad * 4 + i));
#pragma unroll
    for (int nt = 0; nt < 4; ++nt)
#pragma unroll
        for (int i = 0; i < 4; ++i) {
            const int s = q0 + wm + quad * 4 + i;
            const int d = nt * 16 + l15;
            Og[((size_t)(bidx * SEQ + s)) * EMBED + h * HD + d] =
                (bf16_t)(oacc[nt][i] / lf[i]);
        }
}

// ---------------------------------------------------------------------------
// Persistent mega-kernel: QKV-GEMM -> gridbar -> flash -> gridbar -> out-GEMM.
// Grid 512 (2/CU, guaranteed co-resident via __launch_bounds__(256,2), LDS
// 36.8 KB <= 80 KB/2). Eliminates 2 launch gaps + 2 dispatch ramps; flash
// prologue amortized over 2 tiles/block; idle blocks park at the barrier
// (no SIMD issue), giving working blocks full bandwidth.
// ---------------------------------------------------------------------------
__global__ __launch_bounds__(256, 2)
void mega_kernel(const float* __restrict__ x,
                 const float* __restrict__ Wq, const float* __restrict__ bq,
                 const float* __restrict__ Wk, const float* __restrict__ bk,
                 const float* __restrict__ Wv, const float* __restrict__ bv,
                 const float* __restrict__ Wo, const float* __restrict__ bo,
                 float* __restrict__ out,
                 bf16_t* __restrict__ Qw, bf16_t* __restrict__ Kw,
                 bf16_t* __restrict__ Vtw, bf16_t* __restrict__ Ow,
                 u32* __restrict__ bar)
{
    __shared__ __align__(16) char smem[36864];
    bf16_t* As = (bf16_t*)smem;
    bf16_t* Bs = As + 128 * 72;
    bf16_t* KS = (bf16_t*)smem;          // flash: 2 x 4096 elems
    bf16_t* VS = KS + 8192;              //        2 x 4096 elems

    const int bid = blockIdx.x;

    // Phase 1: QKV GEMM — 768 tiles (t = by*64+bx, by in [0,12))
    for (int t = bid; t < 768; t += NBLK)
        gemm_body<0, 128>(t & 63, t >> 6, x, Wq, Wk, Wv, bq, bk, bv,
                          Qw, Kw, Vtw, nullptr, As, Bs);
    gbar(bar);

    // Phase 2: flash — 1024 tiles (t = bh*32+qx), 2 per block
    for (int t = bid; t < 1024; t += NBLK)
        flash_body(t, Qw, Kw, Vtw, Ow, KS, VS);
    gbar(bar);

    // Phase 3: out-proj GEMM — 512 tiles (t = by*64+bx, by in [0,8))
    gemm_body<1, 64>(bid & 63, bid >> 6, Ow, Wo, nullptr, nullptr,
                     bo, nullptr, nullptr, nullptr, nullptr, nullptr, out, As, Bs);
}

extern "C" void kernel_launch(void* const* d_in, const int* in_sizes, int n_in,
                              void* d_out, int out_size, void* d_ws, size_t ws_size,
                              hipStream_t stream)
{
    const float* x  = (const float*)d_in[0];
    const float* Wq = (const float*)d_in[1];
    const float* bq = (const float*)d_in[2];
    const float* Wk = (const float*)d_in[3];
    const float* bk = (const float*)d_in[4];
    const float* Wv = (const float*)d_in[5];
    const float* bv = (const float*)d_in[6];
    const float* Wo = (const float*)d_in[7];
    const float* bo = (const float*)d_in[8];
    float* out = (float*)d_out;

    const size_t NE = (size_t)MTOT * EMBED;   // 4,194,304 elems
    // Layout: Qw = d_out bytes [2NE,4NE) (dead before phase-3 overwrites);
    // barrier state = d_out bytes [0,8) (zeroed per replay; overwritten by
    // phase-3 real output). Kw/Vtw/Ow in ws (25.2 MB as all session).
    bf16_t* Qw  = (bf16_t*)d_out + NE;
    bf16_t* Kw  = (bf16_t*)d_ws;
    bf16_t* Vtw = Kw + NE;
    bf16_t* Ow  = Vtw + NE;
    u32*    bar = (u32*)d_out;

    hipMemsetAsync(bar, 0, 8, stream);
    mega_kernel<<<dim3(NBLK), dim3(256), 0, stream>>>(
        x, Wq, bq, Wk, bk, Wv, bv, Wo, bo, out, Qw, Kw, Vtw, Ow, bar);
}

// Round 10
// 195.608 us; speedup vs baseline: 2.1924x; 2.1924x over previous
//
#include <hip/hip_runtime.h>
#include <hip/hip_bf16.h>

typedef __bf16 bf16_t;
typedef __bf16 bf16x4 __attribute__((ext_vector_type(4)));
typedef __bf16 bf16x8 __attribute__((ext_vector_type(8)));
typedef float  f32x4  __attribute__((ext_vector_type(4)));
typedef float  f32x8  __attribute__((ext_vector_type(8)));
typedef unsigned int u32;
typedef u32 u32x4 __attribute__((ext_vector_type(4)));

#define EMBED 512
#define NH    8
#define HD    64
#define SEQ   2048
#define MTOT  8192
#define SCQ   0.18033688011112042f   // log2(e) / sqrt(64), folded into Q

__device__ __forceinline__ float gelu_f(float x) {
    return 0.5f * x * (1.0f + erff(x * 0.7071067811865475f));
}

__device__ __forceinline__ f32x4 mfma16(bf16x8 a, bf16x8 b, f32x4 c) {
    return __builtin_amdgcn_mfma_f32_16x16x32_bf16(a, b, c, 0, 0, 0);
}

// Raw barrier: LDS-write visibility only (lgkmcnt(0)), NO vmcnt drain.
__device__ __forceinline__ void barrier_nodrain() {
    asm volatile("s_waitcnt lgkmcnt(0)" ::: "memory");
    __builtin_amdgcn_s_barrier();
    asm volatile("" ::: "memory");
}

// Single-instruction exp2 (s is O(+-30): no range fixup needed; avoids any
// libm wrapper VALU around v_exp_f32 — flash is VALU-bound at actual clock).
__device__ __forceinline__ float fast_exp2(float x) {
    float r;
    asm("v_exp_f32 %0, %1" : "=v"(r) : "v"(x));
    return r;
}

// T12 primitives (flash): pack 2 f32 -> 2 bf16, cross-lane register swaps.
__device__ __forceinline__ u32 cvtpk_bf16(float lo, float hi) {
    u32 r;
    asm("v_cvt_pk_bf16_f32 %0, %1, %2" : "=v"(r) : "v"(lo), "v"(hi));
    return r;
}
__device__ __forceinline__ void swap32(u32& a, u32& b) {
    asm volatile("v_permlane32_swap_b32 %0, %1" : "+v"(a), "+v"(b));
}
__device__ __forceinline__ void swap16(u32& a, u32& b) {
    asm volatile("v_permlane16_swap_b32 %0, %1" : "+v"(a), "+v"(b));
}

// ---------------------------------------------------------------------------
// GEMM + bias + GELU.  C[m][n] = gelu( sum_k X[m][k]*W[n][k] + bias[n] )
//
// R10: R8 body (fused fp32 convert, A reg-prefetch, nodrain barriers) with
// LDS 46KB -> 32KB: unpadded stride 64 + XOR swizzle (col ^= (row&7)<<3),
// the same algebra measured conflict-free in flash (R5: conflicts -> 0).
// __launch_bounds__(256,4): LDS now admits 5 blocks/CU (MODE1: 6), raising
// co-residency from 2-3 (R7 measured occupancy 17.7%) — the GEMM is
// latency-stall-bound on its serial inline-W-load chain, and block-level
// overlap is the one resource never yet raised for it.
// ---------------------------------------------------------------------------
template<int MODE, int NTILE>
__global__ __launch_bounds__(256, 4)
void gemm_gelu_kernel(const void*  __restrict__ Xp,
                      const float* __restrict__ W0, const float* __restrict__ W1,
                      const float* __restrict__ W2,
                      const float* __restrict__ Bq, const float* __restrict__ Bk,
                      const float* __restrict__ Bv,
                      bf16_t* __restrict__ O0, bf16_t* __restrict__ O1,
                      bf16_t* __restrict__ O2, float* __restrict__ Of)
{
    constexpr int NTN = NTILE / 32;   // B-staging iters/thr
    __shared__ __align__(16) bf16_t As[128 * 64];
    __shared__ __align__(16) bf16_t Bs[NTILE * 64];
    const int tid  = threadIdx.x;
    const int lane = tid & 63, w = tid >> 6, quad = lane >> 4, l15 = lane & 15;
    const int m0 = blockIdx.x * 128;
    int mat, n0;
    if (MODE == 0) { mat = blockIdx.y >> 2; n0 = (blockIdx.y & 3) * NTILE; }
    else           { mat = 0;               n0 = blockIdx.y * NTILE; }
    const float* W  = (MODE == 0) ? (mat == 0 ? W0 : (mat == 1 ? W1 : W2)) : W0;
    const float* Bi = (MODE == 1) ? Bq : (mat == 0 ? Bq : (mat == 1 ? Bk : Bv));
    const float*  Xf = (const float*)Xp;    // MODE 0
    const bf16_t* Xb = (const bf16_t*)Xp;   // MODE 1

    const int wr = (w >> 1) * 64;            // wave row offset
    const int wc = (w & 1) * (NTILE / 2);    // wave col offset

    const int srow = tid >> 3, scol = (tid & 7) * 8;
    const int ssw  = scol ^ ((srow & 7) << 3);   // swizzled staging col
    const int cxg  = (l15 & 7) << 3;             // read-side swizzle

    f32x4 acc[4][NTN];
#pragma unroll
    for (int a = 0; a < 4; ++a)
#pragma unroll
        for (int b = 0; b < NTN; ++b) acc[a][b] = f32x4{0.f, 0.f, 0.f, 0.f};

    f32x8  xpf[4];   // MODE 0 A prefetch (fp32)
    bf16x8 xpb[4];   // MODE 1 A prefetch (bf16)

    // prologue: A tile 0 -> regs
#pragma unroll
    for (int it = 0; it < 4; ++it) {
        const size_t r = (size_t)(m0 + it * 32 + srow);
        if (MODE == 0) xpf[it] = *(const f32x8*)(Xf + r * EMBED + scol);
        else           xpb[it] = *(const bf16x8*)(Xb + r * EMBED + scol);
    }

#pragma unroll 1
    for (int kt = 0; kt < 8; ++kt) {
        const int k0 = kt * 64;
        barrier_nodrain();   // readers of As/Bs (iter kt-1) are done
        // A: write prefetched regs (convert if fp32); swizzled slot
#pragma unroll
        for (int it = 0; it < 4; ++it) {
            if (MODE == 0)
                *(bf16x8*)(As + (it * 32 + srow) * 64 + ssw) =
                    __builtin_convertvector(xpf[it], bf16x8);
            else
                *(bf16x8*)(As + (it * 32 + srow) * 64 + ssw) = xpb[it];
        }
        // W: inline load+convert+write (L2-hot)
#pragma unroll
        for (int it = 0; it < NTN; ++it) {
            const int r = it * 32 + srow;
            const f32x8 wv = *(const f32x8*)(W + (size_t)(n0 + r) * EMBED + k0 + scol);
            *(bf16x8*)(Bs + r * 64 + ssw) = __builtin_convertvector(wv, bf16x8);
        }
        // A: prefetch tile kt+1
        if (kt < 7) {
            const int k1 = k0 + 64;
#pragma unroll
            for (int it = 0; it < 4; ++it) {
                const size_t r = (size_t)(m0 + it * 32 + srow);
                if (MODE == 0) xpf[it] = *(const f32x8*)(Xf + r * EMBED + k1 + scol);
                else           xpb[it] = *(const bf16x8*)(Xb + r * EMBED + k1 + scol);
            }
        }
        barrier_nodrain();   // As/Bs writes visible to all waves
#pragma unroll
        for (int ks = 0; ks < 2; ++ks) {
            const int ko = ((ks * 4 + quad) * 8) ^ cxg;
            bf16x8 av[4], bv[NTN];
#pragma unroll
            for (int mt = 0; mt < 4; ++mt)
                av[mt] = *(const bf16x8*)(As + (wr + mt * 16 + l15) * 64 + ko);
#pragma unroll
            for (int nt = 0; nt < NTN; ++nt)
                bv[nt] = *(const bf16x8*)(Bs + (wc + nt * 16 + l15) * 64 + ko);
#pragma unroll
            for (int mt = 0; mt < 4; ++mt)
#pragma unroll
                for (int nt = 0; nt < NTN; ++nt)
                    acc[mt][nt] = mfma16(av[mt], bv[nt], acc[mt][nt]);
        }
    }

    // epilogue (C/D layout: col=l15, row=quad*4+i)
    float biasv[NTN];
#pragma unroll
    for (int nt = 0; nt < NTN; ++nt)
        biasv[nt] = Bi[n0 + wc + nt * 16 + l15];
#pragma unroll
    for (int mt = 0; mt < 4; ++mt) {
        const int mb = m0 + wr + mt * 16 + quad * 4;
        const int bb = mb >> 11, s0 = mb & (SEQ - 1);
#pragma unroll
        for (int nt = 0; nt < NTN; ++nt) {
            const int fc = n0 + wc + nt * 16 + l15;
            const int h = fc >> 6, d = fc & 63;
            float vv[4];
#pragma unroll
            for (int i = 0; i < 4; ++i) vv[i] = gelu_f(acc[mt][nt][i] + biasv[nt]);
            if (MODE == 1) {
#pragma unroll
                for (int i = 0; i < 4; ++i) Of[(size_t)(mb + i) * EMBED + fc] = vv[i];
            } else if (mat == 0) {
#pragma unroll
                for (int i = 0; i < 4; ++i)
                    O0[(((size_t)(bb * NH + h)) * SEQ + s0 + i) * HD + d] = (bf16_t)(vv[i] * SCQ);
            } else if (mat == 1) {
#pragma unroll
                for (int i = 0; i < 4; ++i)
                    O1[(((size_t)(bb * NH + h)) * SEQ + s0 + i) * HD + d] = (bf16_t)vv[i];
            } else {
                bf16x4 pk;
#pragma unroll
                for (int i = 0; i < 4; ++i) pk[i] = (bf16_t)vv[i];
                *(bf16x4*)(O2 + ((size_t)(bb * NH + h) * HD + d) * SEQ + s0) = pk;
            }
        }
    }
}

// ---------------------------------------------------------------------------
// Flash attention — R5-R8 structure (67.4-68.4 µs stable, conflicts 0, T12
// in-reg P). Only change: exp2f -> raw v_exp_f32 (VALU-bound at actual clock).
// ---------------------------------------------------------------------------
#define FA_ITER(T, BUF, KR0, KR1, VR0, VR1)                                   \
    do {                                                                      \
        if ((T) + 1 < 32) {                                                   \
            bf16_t* Kn = Ks[(BUF) ^ 1];                                       \
            bf16_t* Vn = Vs[(BUF) ^ 1];                                       \
            *(bf16x8*)(Kn + sA)        = KR0;                                 \
            *(bf16x8*)(Kn + sA + 2048) = KR1;                                 \
            *(bf16x8*)(Vn + sA)        = VR0;                                 \
            *(bf16x8*)(Vn + sA + 2048) = VR1;                                 \
        }                                                                     \
        if ((T) + 3 < 32) {                                                   \
            const int kv = ((T) + 3) * 64;                                    \
            KR0 = *(const bf16x8*)(K + baseQK + (size_t)(kv + r0) * HD + c0); \
            KR1 = *(const bf16x8*)(K + baseQK + (size_t)(kv + r0 + 32) * HD + c0); \
            VR0 = *(const bf16x8*)(Vt + baseV + (size_t)r0 * SEQ + kv + c0);  \
            VR1 = *(const bf16x8*)(Vt + baseV + (size_t)(r0 + 32) * SEQ + kv + c0); \
        }                                                                     \
        const bf16_t* Kb = Ks[(BUF)];                                         \
        const bf16_t* Vb = Vs[(BUF)];                                         \
        f32x4 sf[4];                                                          \
        _Pragma("unroll")                                                     \
        for (int jt = 0; jt < 4; ++jt) sf[jt] = f32x4{0.f, 0.f, 0.f, 0.f};    \
        __builtin_amdgcn_s_setprio(1);                                        \
        _Pragma("unroll")                                                     \
        for (int ks = 0; ks < 2; ++ks) {                                      \
            const int ko = (ks * 32 + quad * 8) ^ cx;                         \
            _Pragma("unroll")                                                 \
            for (int jt = 0; jt < 4; ++jt) {                                  \
                const bf16x8 a = *(const bf16x8*)(Kb + ((jt * 16 + l15) << 6) + ko); \
                sf[jt] = mfma16(a, qf[ks], sf[jt]);                           \
            }                                                                 \
        }                                                                     \
        __builtin_amdgcn_s_setprio(0);                                        \
        u32 w0[4], w1[4];                                                     \
        _Pragma("unroll")                                                     \
        for (int jt = 0; jt < 4; ++jt) {                                      \
            _Pragma("unroll")                                                 \
            for (int i = 0; i < 4; ++i) sf[jt][i] = fast_exp2(sf[jt][i]);     \
            lacc += sf[jt];                                                   \
            w0[jt] = cvtpk_bf16(sf[jt][0], sf[jt][1]);                        \
            w1[jt] = cvtpk_bf16(sf[jt][2], sf[jt][3]);                        \
        }                                                                     \
        swap32(w0[0], w0[1]); swap16(w0[0], w0[1]);                           \
        swap32(w1[0], w1[1]); swap16(w1[0], w1[1]);                           \
        swap32(w0[2], w0[3]); swap16(w0[2], w0[3]);                           \
        swap32(w1[2], w1[3]); swap16(w1[2], w1[3]);                           \
        const u32x4 pq0 = u32x4{w0[0], w1[0], w0[1], w1[1]};                  \
        const u32x4 pq1 = u32x4{w0[2], w1[2], w0[3], w1[3]};                  \
        const bf16x8 pa0 = __builtin_bit_cast(bf16x8, pq0);                   \
        const bf16x8 pa1 = __builtin_bit_cast(bf16x8, pq1);                   \
        __builtin_amdgcn_s_setprio(1);                                        \
        _Pragma("unroll")                                                     \
        for (int c = 0; c < 2; ++c) {                                         \
            const int ko = (c * 32 + quad * 8) ^ cx;                          \
            const bf16x8 pa = c ? pa1 : pa0;                                  \
            _Pragma("unroll")                                                 \
            for (int nt = 0; nt < 4; ++nt) {                                  \
                const bf16x8 b = *(const bf16x8*)(Vb + ((nt * 16 + l15) << 6) + ko); \
                oacc[nt] = mfma16(pa, b, oacc[nt]);                           \
            }                                                                 \
        }                                                                     \
        __builtin_amdgcn_s_setprio(0);                                        \
        if ((T) < 31) barrier_nodrain();                                      \
    } while (0)

__global__ __launch_bounds__(256, 4)
void flash_attn_kernel(const bf16_t* __restrict__ Q,
                       const bf16_t* __restrict__ K,
                       const bf16_t* __restrict__ Vt,
                       bf16_t* __restrict__ Og)
{
    __shared__ __align__(16) bf16_t Ks[2][64 * 64];
    __shared__ __align__(16) bf16_t Vs[2][64 * 64];

    const int tid  = threadIdx.x;
    const int lane = tid & 63, w = tid >> 6, quad = lane >> 4, l15 = lane & 15;
    const int bh = blockIdx.y;
    const int q0 = blockIdx.x * 64;
    const size_t baseQK = (size_t)bh * SEQ * HD;
    const size_t baseV  = (size_t)bh * HD * SEQ;
    const int wm = w * 16;
    const int cx = (l15 & 7) << 3;

    bf16x8 qf[2];
#pragma unroll
    for (int ks = 0; ks < 2; ++ks)
        qf[ks] = *(const bf16x8*)(Q + baseQK + (size_t)(q0 + wm + l15) * HD + ks * 32 + quad * 8);

    f32x4 lacc = f32x4{0.f, 0.f, 0.f, 0.f};
    f32x4 oacc[4];
#pragma unroll
    for (int nt = 0; nt < 4; ++nt) oacc[nt] = f32x4{0.f, 0.f, 0.f, 0.f};

    const int r0 = tid >> 3, c0 = (tid & 7) * 8;
    const int sA = (r0 << 6) + (c0 ^ ((r0 & 7) << 3));

    bf16x8 kA0, kA1, vA0, vA1;
    bf16x8 kB0, kB1, vB0, vB1;

    kA0 = *(const bf16x8*)(K + baseQK + (size_t)r0 * HD + c0);
    kA1 = *(const bf16x8*)(K + baseQK + (size_t)(r0 + 32) * HD + c0);
    vA0 = *(const bf16x8*)(Vt + baseV + (size_t)r0 * SEQ + c0);
    vA1 = *(const bf16x8*)(Vt + baseV + (size_t)(r0 + 32) * SEQ + c0);
    *(bf16x8*)(Ks[0] + sA)        = kA0;
    *(bf16x8*)(Ks[0] + sA + 2048) = kA1;
    *(bf16x8*)(Vs[0] + sA)        = vA0;
    *(bf16x8*)(Vs[0] + sA + 2048) = vA1;
    kB0 = *(const bf16x8*)(K + baseQK + (size_t)(64 + r0) * HD + c0);
    kB1 = *(const bf16x8*)(K + baseQK + (size_t)(64 + r0 + 32) * HD + c0);
    vB0 = *(const bf16x8*)(Vt + baseV + (size_t)r0 * SEQ + 64 + c0);
    vB1 = *(const bf16x8*)(Vt + baseV + (size_t)(r0 + 32) * SEQ + 64 + c0);
    kA0 = *(const bf16x8*)(K + baseQK + (size_t)(128 + r0) * HD + c0);
    kA1 = *(const bf16x8*)(K + baseQK + (size_t)(128 + r0 + 32) * HD + c0);
    vA0 = *(const bf16x8*)(Vt + baseV + (size_t)r0 * SEQ + 128 + c0);
    vA1 = *(const bf16x8*)(Vt + baseV + (size_t)(r0 + 32) * SEQ + 128 + c0);
    barrier_nodrain();

#pragma unroll 1
    for (int tt = 0; tt < 32; tt += 2) {
        FA_ITER(tt,     0, kB0, kB1, vB0, vB1);
        FA_ITER(tt + 1, 1, kA0, kA1, vA0, vA1);
    }

    const int bidx = bh >> 3, h = bh & 7;
    float rs = (lacc[0] + lacc[1]) + (lacc[2] + lacc[3]);
    rs += __shfl_xor(rs, 16);
    rs += __shfl_xor(rs, 32);
    float lf[4];
#pragma unroll
    for (int i = 0; i < 4; ++i)
        lf[i] = __shfl(rs, (lane & 48) | (quad * 4 + i));
#pragma unroll
    for (int nt = 0; nt < 4; ++nt)
#pragma unroll
        for (int i = 0; i < 4; ++i) {
            const int s = q0 + wm + quad * 4 + i;
            const int d = nt * 16 + l15;
            Og[((size_t)(bidx * SEQ + s)) * EMBED + h * HD + d] =
                (bf16_t)(oacc[nt][i] / lf[i]);
        }
}

extern "C" void kernel_launch(void* const* d_in, const int* in_sizes, int n_in,
                              void* d_out, int out_size, void* d_ws, size_t ws_size,
                              hipStream_t stream)
{
    const float* x  = (const float*)d_in[0];
    const float* Wq = (const float*)d_in[1];
    const float* bq = (const float*)d_in[2];
    const float* Wk = (const float*)d_in[3];
    const float* bk = (const float*)d_in[4];
    const float* Wv = (const float*)d_in[5];
    const float* bv = (const float*)d_in[6];
    const float* Wo = (const float*)d_in[7];
    const float* bo = (const float*)d_in[8];
    float* out = (float*)d_out;

    const size_t NE = (size_t)MTOT * EMBED;   // 4,194,304 elems
    // Layout (R8): Qw in d_out's 2nd half (dead before final fp32 out
    // overwrite); Kw / Vtw / Ow in ws. Convert fused into the QKV GEMM.
    bf16_t* Qw  = (bf16_t*)d_out + NE;
    bf16_t* Kw  = (bf16_t*)d_ws;
    bf16_t* Vtw = Kw + NE;
    bf16_t* Ow  = Vtw + NE;

    gemm_gelu_kernel<0, 128><<<dim3(64, 12), 256, 0, stream>>>(
        x, Wq, Wk, Wv, bq, bk, bv, Qw, Kw, Vtw, nullptr);
    flash_attn_kernel<<<dim3(32, 32), 256, 0, stream>>>(Qw, Kw, Vtw, Ow);
    gemm_gelu_kernel<1, 64><<<dim3(64, 8), 256, 0, stream>>>(
        Ow, Wo, nullptr, nullptr, bo, nullptr, nullptr,
        nullptr, nullptr, nullptr, out);
}

// Round 11
// 168.570 us; speedup vs baseline: 2.5441x; 1.1604x over previous
//
#include <hip/hip_runtime.h>
#include <hip/hip_bf16.h>

typedef __bf16 bf16_t;
typedef __bf16 bf16x4 __attribute__((ext_vector_type(4)));
typedef __bf16 bf16x8 __attribute__((ext_vector_type(8)));
typedef float  f32x4  __attribute__((ext_vector_type(4)));
typedef float  f32x8  __attribute__((ext_vector_type(8)));
typedef unsigned int u32;
typedef u32 u32x4 __attribute__((ext_vector_type(4)));

#define EMBED 512
#define NH    8
#define HD    64
#define SEQ   2048
#define MTOT  8192
#define SCQ   0.18033688011112042f   // log2(e) / sqrt(64), folded into Q

__device__ __forceinline__ float gelu_f(float x) {
    return 0.5f * x * (1.0f + erff(x * 0.7071067811865475f));
}

__device__ __forceinline__ f32x4 mfma16(bf16x8 a, bf16x8 b, f32x4 c) {
    return __builtin_amdgcn_mfma_f32_16x16x32_bf16(a, b, c, 0, 0, 0);
}

// Raw barrier: LDS-write visibility only (lgkmcnt(0)), NO vmcnt drain —
// global prefetch loads stay in flight across the barrier; the compiler
// emits counted vmcnt waits at the dependent use.
__device__ __forceinline__ void barrier_nodrain() {
    asm volatile("s_waitcnt lgkmcnt(0)" ::: "memory");
    __builtin_amdgcn_s_barrier();
    asm volatile("" ::: "memory");
}

// Single-instruction exp2 (R10-proven: flash 68.4 -> <64.5 µs; scores are
// O(1) so no libm range fixup needed).
__device__ __forceinline__ float fast_exp2(float x) {
    float r;
    asm("v_exp_f32 %0, %1" : "=v"(r) : "v"(x));
    return r;
}

// T12 primitives (flash): pack 2 f32 -> 2 bf16, cross-lane register swaps.
__device__ __forceinline__ u32 cvtpk_bf16(float lo, float hi) {
    u32 r;
    asm("v_cvt_pk_bf16_f32 %0, %1, %2" : "=v"(r) : "v"(lo), "v"(hi));
    return r;
}
__device__ __forceinline__ void swap32(u32& a, u32& b) {
    asm volatile("v_permlane32_swap_b32 %0, %1" : "+v"(a), "+v"(b));
}
__device__ __forceinline__ void swap16(u32& a, u32& b) {
    asm volatile("v_permlane16_swap_b32 %0, %1" : "+v"(a), "+v"(b));
}

// ---------------------------------------------------------------------------
// GEMM + bias + GELU — EXACT R8 configuration (the 179.4 µs session best):
// fused fp32 convert, A reg-prefetch across nodrain barriers, inline W
// convert, padded-72 LDS (<=2-way conflicts = free), __launch_bounds__(256,3).
// R10's swizzle+(256,4) variant REVERTED: occupancy 17.7->30% bought ~2 µs
// (GEMM not occupancy-bound — 6th falsified lever) and induced 2.4x V-write
// amplification (WRITE 24.6->60 MB, XCD L2 partial-line thrash).
// ---------------------------------------------------------------------------
template<int MODE, int NTILE>
__global__ __launch_bounds__(256, 3)
void gemm_gelu_kernel(const void*  __restrict__ Xp,
                      const float* __restrict__ W0, const float* __restrict__ W1,
                      const float* __restrict__ W2,
                      const float* __restrict__ Bq, const float* __restrict__ Bk,
                      const float* __restrict__ Bv,
                      bf16_t* __restrict__ O0, bf16_t* __restrict__ O1,
                      bf16_t* __restrict__ O2, float* __restrict__ Of)
{
    constexpr int NTN = NTILE / 32;   // B-staging iters/thr
    __shared__ __align__(16) bf16_t As[128 * 72];
    __shared__ __align__(16) bf16_t Bs[NTILE * 72];
    const int tid  = threadIdx.x;
    const int lane = tid & 63, w = tid >> 6, quad = lane >> 4, l15 = lane & 15;
    const int m0 = blockIdx.x * 128;
    int mat, n0;
    if (MODE == 0) { mat = blockIdx.y >> 2; n0 = (blockIdx.y & 3) * NTILE; }
    else           { mat = 0;               n0 = blockIdx.y * NTILE; }
    const float* W  = (MODE == 0) ? (mat == 0 ? W0 : (mat == 1 ? W1 : W2)) : W0;
    const float* Bi = (MODE == 1) ? Bq : (mat == 0 ? Bq : (mat == 1 ? Bk : Bv));
    const float*  Xf = (const float*)Xp;    // MODE 0
    const bf16_t* Xb = (const bf16_t*)Xp;   // MODE 1

    const int wr = (w >> 1) * 64;            // wave row offset
    const int wc = (w & 1) * (NTILE / 2);    // wave col offset

    const int srow = tid >> 3, scol = (tid & 7) * 8;

    f32x4 acc[4][NTN];
#pragma unroll
    for (int a = 0; a < 4; ++a)
#pragma unroll
        for (int b = 0; b < NTN; ++b) acc[a][b] = f32x4{0.f, 0.f, 0.f, 0.f};

    f32x8  xpf[4];   // MODE 0 A prefetch (fp32)
    bf16x8 xpb[4];   // MODE 1 A prefetch (bf16)

    // prologue: A tile 0 -> regs
#pragma unroll
    for (int it = 0; it < 4; ++it) {
        const size_t r = (size_t)(m0 + it * 32 + srow);
        if (MODE == 0) xpf[it] = *(const f32x8*)(Xf + r * EMBED + scol);
        else           xpb[it] = *(const bf16x8*)(Xb + r * EMBED + scol);
    }

#pragma unroll 1
    for (int kt = 0; kt < 8; ++kt) {
        const int k0 = kt * 64;
        barrier_nodrain();   // readers of As/Bs (iter kt-1) are done
        // A: write prefetched regs (convert if fp32)
#pragma unroll
        for (int it = 0; it < 4; ++it) {
            if (MODE == 0)
                *(bf16x8*)(As + (it * 32 + srow) * 72 + scol) =
                    __builtin_convertvector(xpf[it], bf16x8);
            else
                *(bf16x8*)(As + (it * 32 + srow) * 72 + scol) = xpb[it];
        }
        // W: inline load+convert+write (L2-hot; no cross-barrier regs)
#pragma unroll
        for (int it = 0; it < NTN; ++it) {
            const int r = it * 32 + srow;
            const f32x8 wv = *(const f32x8*)(W + (size_t)(n0 + r) * EMBED + k0 + scol);
            *(bf16x8*)(Bs + r * 72 + scol) = __builtin_convertvector(wv, bf16x8);
        }
        // A: prefetch tile kt+1
        if (kt < 7) {
            const int k1 = k0 + 64;
#pragma unroll
            for (int it = 0; it < 4; ++it) {
                const size_t r = (size_t)(m0 + it * 32 + srow);
                if (MODE == 0) xpf[it] = *(const f32x8*)(Xf + r * EMBED + k1 + scol);
                else           xpb[it] = *(const bf16x8*)(Xb + r * EMBED + k1 + scol);
            }
        }
        barrier_nodrain();   // As/Bs writes visible to all waves
#pragma unroll
        for (int ks = 0; ks < 2; ++ks) {
            const int ko = (ks * 4 + quad) * 8;
            bf16x8 av[4], bv[NTN];
#pragma unroll
            for (int mt = 0; mt < 4; ++mt)
                av[mt] = *(const bf16x8*)(As + (wr + mt * 16 + l15) * 72 + ko);
#pragma unroll
            for (int nt = 0; nt < NTN; ++nt)
                bv[nt] = *(const bf16x8*)(Bs + (wc + nt * 16 + l15) * 72 + ko);
#pragma unroll
            for (int mt = 0; mt < 4; ++mt)
#pragma unroll
                for (int nt = 0; nt < NTN; ++nt)
                    acc[mt][nt] = mfma16(av[mt], bv[nt], acc[mt][nt]);
        }
    }

    // epilogue (C/D layout: col=l15, row=quad*4+i)
    float biasv[NTN];
#pragma unroll
    for (int nt = 0; nt < NTN; ++nt)
        biasv[nt] = Bi[n0 + wc + nt * 16 + l15];
#pragma unroll
    for (int mt = 0; mt < 4; ++mt) {
        const int mb = m0 + wr + mt * 16 + quad * 4;
        const int bb = mb >> 11, s0 = mb & (SEQ - 1);
#pragma unroll
        for (int nt = 0; nt < NTN; ++nt) {
            const int fc = n0 + wc + nt * 16 + l15;
            const int h = fc >> 6, d = fc & 63;
            float vv[4];
#pragma unroll
            for (int i = 0; i < 4; ++i) vv[i] = gelu_f(acc[mt][nt][i] + biasv[nt]);
            if (MODE == 1) {
#pragma unroll
                for (int i = 0; i < 4; ++i) Of[(size_t)(mb + i) * EMBED + fc] = vv[i];
            } else if (mat == 0) {
#pragma unroll
                for (int i = 0; i < 4; ++i)
                    O0[(((size_t)(bb * NH + h)) * SEQ + s0 + i) * HD + d] = (bf16_t)(vv[i] * SCQ);
            } else if (mat == 1) {
#pragma unroll
                for (int i = 0; i < 4; ++i)
                    O1[(((size_t)(bb * NH + h)) * SEQ + s0 + i) * HD + d] = (bf16_t)vv[i];
            } else {
                bf16x4 pk;
#pragma unroll
                for (int i = 0; i < 4; ++i) pk[i] = (bf16_t)vv[i];
                *(bf16x4*)(O2 + ((size_t)(bb * NH + h) * HD + d) * SEQ + s0) = pk;
            }
        }
    }
}

// ---------------------------------------------------------------------------
// Flash attention — R5-R8 structure + R10's fast_exp2 (the one flash win
// since R5: 68.4 -> <64.5 µs). Conflicts 0, T12 in-reg P, nodrain barriers,
// 2-tile-deep A/B register prefetch.
// ---------------------------------------------------------------------------
#define FA_ITER(T, BUF, KR0, KR1, VR0, VR1)                                   \
    do {                                                                      \
        if ((T) + 1 < 32) {                                                   \
            bf16_t* Kn = Ks[(BUF) ^ 1];                                       \
            bf16_t* Vn = Vs[(BUF) ^ 1];                                       \
            *(bf16x8*)(Kn + sA)        = KR0;                                 \
            *(bf16x8*)(Kn + sA + 2048) = KR1;                                 \
            *(bf16x8*)(Vn + sA)        = VR0;                                 \
            *(bf16x8*)(Vn + sA + 2048) = VR1;                                 \
        }                                                                     \
        if ((T) + 3 < 32) {                                                   \
            const int kv = ((T) + 3) * 64;                                    \
            KR0 = *(const bf16x8*)(K + baseQK + (size_t)(kv + r0) * HD + c0); \
            KR1 = *(const bf16x8*)(K + baseQK + (size_t)(kv + r0 + 32) * HD + c0); \
            VR0 = *(const bf16x8*)(Vt + baseV + (size_t)r0 * SEQ + kv + c0);  \
            VR1 = *(const bf16x8*)(Vt + baseV + (size_t)(r0 + 32) * SEQ + kv + c0); \
        }                                                                     \
        const bf16_t* Kb = Ks[(BUF)];                                         \
        const bf16_t* Vb = Vs[(BUF)];                                         \
        f32x4 sf[4];                                                          \
        _Pragma("unroll")                                                     \
        for (int jt = 0; jt < 4; ++jt) sf[jt] = f32x4{0.f, 0.f, 0.f, 0.f};    \
        __builtin_amdgcn_s_setprio(1);                                        \
        _Pragma("unroll")                                                     \
        for (int ks = 0; ks < 2; ++ks) {                                      \
            const int ko = (ks * 32 + quad * 8) ^ cx;                         \
            _Pragma("unroll")                                                 \
            for (int jt = 0; jt < 4; ++jt) {                                  \
                const bf16x8 a = *(const bf16x8*)(Kb + ((jt * 16 + l15) << 6) + ko); \
                sf[jt] = mfma16(a, qf[ks], sf[jt]);                           \
            }                                                                 \
        }                                                                     \
        __builtin_amdgcn_s_setprio(0);                                        \
        u32 w0[4], w1[4];                                                     \
        _Pragma("unroll")                                                     \
        for (int jt = 0; jt < 4; ++jt) {                                      \
            _Pragma("unroll")                                                 \
            for (int i = 0; i < 4; ++i) sf[jt][i] = fast_exp2(sf[jt][i]);     \
            lacc += sf[jt];                                                   \
            w0[jt] = cvtpk_bf16(sf[jt][0], sf[jt][1]);                        \
            w1[jt] = cvtpk_bf16(sf[jt][2], sf[jt][3]);                        \
        }                                                                     \
        swap32(w0[0], w0[1]); swap16(w0[0], w0[1]);                           \
        swap32(w1[0], w1[1]); swap16(w1[0], w1[1]);                           \
        swap32(w0[2], w0[3]); swap16(w0[2], w0[3]);                           \
        swap32(w1[2], w1[3]); swap16(w1[2], w1[3]);                           \
        const u32x4 pq0 = u32x4{w0[0], w1[0], w0[1], w1[1]};                  \
        const u32x4 pq1 = u32x4{w0[2], w1[2], w0[3], w1[3]};                  \
        const bf16x8 pa0 = __builtin_bit_cast(bf16x8, pq0);                   \
        const bf16x8 pa1 = __builtin_bit_cast(bf16x8, pq1);                   \
        __builtin_amdgcn_s_setprio(1);                                        \
        _Pragma("unroll")                                                     \
        for (int c = 0; c < 2; ++c) {                                         \
            const int ko = (c * 32 + quad * 8) ^ cx;                          \
            const bf16x8 pa = c ? pa1 : pa0;                                  \
            _Pragma("unroll")                                                 \
            for (int nt = 0; nt < 4; ++nt) {                                  \
                const bf16x8 b = *(const bf16x8*)(Vb + ((nt * 16 + l15) << 6) + ko); \
                oacc[nt] = mfma16(pa, b, oacc[nt]);                           \
            }                                                                 \
        }                                                                     \
        __builtin_amdgcn_s_setprio(0);                                        \
        if ((T) < 31) barrier_nodrain();                                      \
    } while (0)

__global__ __launch_bounds__(256, 4)
void flash_attn_kernel(const bf16_t* __restrict__ Q,
                       const bf16_t* __restrict__ K,
                       const bf16_t* __restrict__ Vt,
                       bf16_t* __restrict__ Og)
{
    __shared__ __align__(16) bf16_t Ks[2][64 * 64];
    __shared__ __align__(16) bf16_t Vs[2][64 * 64];

    const int tid  = threadIdx.x;
    const int lane = tid & 63, w = tid >> 6, quad = lane >> 4, l15 = lane & 15;
    const int bh = blockIdx.y;
    const int q0 = blockIdx.x * 64;
    const size_t baseQK = (size_t)bh * SEQ * HD;
    const size_t baseV  = (size_t)bh * HD * SEQ;
    const int wm = w * 16;
    const int cx = (l15 & 7) << 3;

    bf16x8 qf[2];
#pragma unroll
    for (int ks = 0; ks < 2; ++ks)
        qf[ks] = *(const bf16x8*)(Q + baseQK + (size_t)(q0 + wm + l15) * HD + ks * 32 + quad * 8);

    f32x4 lacc = f32x4{0.f, 0.f, 0.f, 0.f};
    f32x4 oacc[4];
#pragma unroll
    for (int nt = 0; nt < 4; ++nt) oacc[nt] = f32x4{0.f, 0.f, 0.f, 0.f};

    const int r0 = tid >> 3, c0 = (tid & 7) * 8;
    const int sA = (r0 << 6) + (c0 ^ ((r0 & 7) << 3));

    bf16x8 kA0, kA1, vA0, vA1;
    bf16x8 kB0, kB1, vB0, vB1;

    kA0 = *(const bf16x8*)(K + baseQK + (size_t)r0 * HD + c0);
    kA1 = *(const bf16x8*)(K + baseQK + (size_t)(r0 + 32) * HD + c0);
    vA0 = *(const bf16x8*)(Vt + baseV + (size_t)r0 * SEQ + c0);
    vA1 = *(const bf16x8*)(Vt + baseV + (size_t)(r0 + 32) * SEQ + c0);
    *(bf16x8*)(Ks[0] + sA)        = kA0;
    *(bf16x8*)(Ks[0] + sA + 2048) = kA1;
    *(bf16x8*)(Vs[0] + sA)        = vA0;
    *(bf16x8*)(Vs[0] + sA + 2048) = vA1;
    kB0 = *(const bf16x8*)(K + baseQK + (size_t)(64 + r0) * HD + c0);
    kB1 = *(const bf16x8*)(K + baseQK + (size_t)(64 + r0 + 32) * HD + c0);
    vB0 = *(const bf16x8*)(Vt + baseV + (size_t)r0 * SEQ + 64 + c0);
    vB1 = *(const bf16x8*)(Vt + baseV + (size_t)(r0 + 32) * SEQ + 64 + c0);
    kA0 = *(const bf16x8*)(K + baseQK + (size_t)(128 + r0) * HD + c0);
    kA1 = *(const bf16x8*)(K + baseQK + (size_t)(128 + r0 + 32) * HD + c0);
    vA0 = *(const bf16x8*)(Vt + baseV + (size_t)r0 * SEQ + 128 + c0);
    vA1 = *(const bf16x8*)(Vt + baseV + (size_t)(r0 + 32) * SEQ + 128 + c0);
    barrier_nodrain();

#pragma unroll 1
    for (int tt = 0; tt < 32; tt += 2) {
        FA_ITER(tt,     0, kB0, kB1, vB0, vB1);
        FA_ITER(tt + 1, 1, kA0, kA1, vA0, vA1);
    }

    const int bidx = bh >> 3, h = bh & 7;
    float rs = (lacc[0] + lacc[1]) + (lacc[2] + lacc[3]);
    rs += __shfl_xor(rs, 16);
    rs += __shfl_xor(rs, 32);
    float lf[4];
#pragma unroll
    for (int i = 0; i < 4; ++i)
        lf[i] = __shfl(rs, (lane & 48) | (quad * 4 + i));
#pragma unroll
    for (int nt = 0; nt < 4; ++nt)
#pragma unroll
        for (int i = 0; i < 4; ++i) {
            const int s = q0 + wm + quad * 4 + i;
            const int d = nt * 16 + l15;
            Og[((size_t)(bidx * SEQ + s)) * EMBED + h * HD + d] =
                (bf16_t)(oacc[nt][i] / lf[i]);
        }
}

extern "C" void kernel_launch(void* const* d_in, const int* in_sizes, int n_in,
                              void* d_out, int out_size, void* d_ws, size_t ws_size,
                              hipStream_t stream)
{
    const float* x  = (const float*)d_in[0];
    const float* Wq = (const float*)d_in[1];
    const float* bq = (const float*)d_in[2];
    const float* Wk = (const float*)d_in[3];
    const float* bk = (const float*)d_in[4];
    const float* Wv = (const float*)d_in[5];
    const float* bv = (const float*)d_in[6];
    const float* Wo = (const float*)d_in[7];
    const float* bo = (const float*)d_in[8];
    float* out = (float*)d_out;

    const size_t NE = (size_t)MTOT * EMBED;   // 4,194,304 elems
    // Layout (R8): Qw in d_out's 2nd half (dead before final fp32 out
    // overwrite); Kw / Vtw / Ow in ws. Convert fused into the QKV GEMM.
    bf16_t* Qw  = (bf16_t*)d_out + NE;
    bf16_t* Kw  = (bf16_t*)d_ws;
    bf16_t* Vtw = Kw + NE;
    bf16_t* Ow  = Vtw + NE;

    gemm_gelu_kernel<0, 128><<<dim3(64, 12), 256, 0, stream>>>(
        x, Wq, Wk, Wv, bq, bk, bv, Qw, Kw, Vtw, nullptr);
    flash_attn_kernel<<<dim3(32, 32), 256, 0, stream>>>(Qw, Kw, Vtw, Ow);
    gemm_gelu_kernel<1, 64><<<dim3(64, 8), 256, 0, stream>>>(
        Ow, Wo, nullptr, nullptr, bo, nullptr, nullptr,
        nullptr, nullptr, nullptr, out);
}